// Round 6
// baseline (161.129 us; speedup 1.0000x reference)
//
#include <hip/hip_runtime.h>

// QuantileLoss: mean over [ (p0-t0)^2, (p1-t1)^2, (p2-t2)^2, lower, upper ]
//   lower = p3>p2 ? (p4-t2)*4 : (p3>0.95*t2 ? 0 : (p3-0.95*t2)^2)
//   upper = p4<p2 ? (p4-t2)*4 : (p4<1.05*t2 ? 0 : (p4-1.05*t2)^2)
//
// R5 post-mortem: LDS-staged variants plateau at ~45-50us regardless of
// occupancy/pipeline depth -> the global->ds_write->ds_read->VALU chain is
// the suspect. R1's direct per-lane row-group loads were never measured
// without the single-address atomic (which alone explains R1's 61us and
// R2's 205us at ~15ns/block). R6: R1 data path (4 rows/lane = 5+3 float4,
// constant-index union, no LDS, no barriers, 8 independent loads in flight
// per lane) + R3 reduction (per-block partials, no atomics), int32 addressing.

#define BLOCK 256
#define RPT   4   // rows per thread

__device__ __forceinline__ float row_loss(float p0, float p1, float p2,
                                          float p3, float p4,
                                          float t0, float t1, float t2) {
    float d0 = p0 - t0, d1 = p1 - t1, d2 = p2 - t2;
    float acc = d0 * d0 + d1 * d1 + d2 * d2;
    float tl = t2 * 0.95f;
    float tu = t2 * 1.05f;
    float pen = (p4 - t2) * 4.0f;
    float dl = p3 - tl;
    float du = p4 - tu;
    float lower = (p3 > p2) ? pen : ((p3 > tl) ? 0.0f : dl * dl);
    float upper = (p4 < p2) ? pen : ((p4 < tu) ? 0.0f : du * du);
    return acc + lower + upper;
}

__global__ __launch_bounds__(BLOCK) void ql_main(const float* __restrict__ preds,
                                                 const float* __restrict__ target,
                                                 double* __restrict__ ws,
                                                 int ngroups) {
    const int g = blockIdx.x * BLOCK + threadIdx.x;   // 4-row group index
    float acc = 0.0f;

    if (g < ngroups) {
        // 8 independent float4 loads, issued before any use (no LDS hop)
        const float4* pp = (const float4*)preds + g * 5;
        const float4* tp = (const float4*)target + g * 3;
        union { float4 v[5]; float f[20]; } P;
        union { float4 v[3]; float f[12]; } T;
        P.v[0] = pp[0]; P.v[1] = pp[1]; P.v[2] = pp[2]; P.v[3] = pp[3]; P.v[4] = pp[4];
        T.v[0] = tp[0]; T.v[1] = tp[1]; T.v[2] = tp[2];
#pragma unroll
        for (int j = 0; j < RPT; ++j) {
            acc += row_loss(P.f[5 * j + 0], P.f[5 * j + 1], P.f[5 * j + 2],
                            P.f[5 * j + 3], P.f[5 * j + 4],
                            T.f[3 * j + 0], T.f[3 * j + 1], T.f[3 * j + 2]);
        }
    }

    // wave reduction (double), cross-wave via LDS, one plain store per block
    double dacc = (double)acc;
#pragma unroll
    for (int off = 32; off > 0; off >>= 1)
        dacc += __shfl_down(dacc, off, 64);

    __shared__ double wsum[BLOCK / 64];
    int lane = threadIdx.x & 63;
    int w = threadIdx.x >> 6;
    if (lane == 0) wsum[w] = dacc;
    __syncthreads();
    if (threadIdx.x == 0)
        ws[blockIdx.x] = wsum[0] + wsum[1] + wsum[2] + wsum[3];
}

__global__ __launch_bounds__(256) void ql_finalize(const double* __restrict__ ws,
                                                   int nblk,
                                                   const float* __restrict__ preds,
                                                   const float* __restrict__ target,
                                                   float* __restrict__ out,
                                                   long rows, long tail_start) {
    __shared__ double wsum[4];
    const int tid = threadIdx.x;

    double d = 0.0;
    for (int i = tid; i < nblk; i += 256)
        d += ws[i];

    // rows not covered by full 4-row groups (none for N=4194304)
    for (long r = tail_start + tid; r < rows; r += 256) {
        const float* p = preds + r * 5;
        const float* tg = target + r * 3;
        d += (double)row_loss(p[0], p[1], p[2], p[3], p[4], tg[0], tg[1], tg[2]);
    }

#pragma unroll
    for (int off = 32; off > 0; off >>= 1)
        d += __shfl_down(d, off, 64);
    int lane = tid & 63, w = tid >> 6;
    if (lane == 0) wsum[w] = d;
    __syncthreads();
    if (tid == 0) {
        double total = wsum[0] + wsum[1] + wsum[2] + wsum[3];
        out[0] = (float)(total / ((double)rows * 5.0));
    }
}

extern "C" void kernel_launch(void* const* d_in, const int* in_sizes, int n_in,
                              void* d_out, int out_size, void* d_ws, size_t ws_size,
                              hipStream_t stream) {
    const float* preds = (const float*)d_in[0];
    const float* target = (const float*)d_in[1];
    long rows = (long)in_sizes[0] / 5;
    int ngroups = (int)(rows / RPT);          // full 4-row groups
    long tail_start = (long)ngroups * RPT;

    int nblk = (ngroups + BLOCK - 1) / BLOCK; // 4096 for N=4194304
    double* partials = (double*)d_ws;         // nblk doubles (32 KB)

    ql_main<<<nblk, BLOCK, 0, stream>>>(preds, target, partials, ngroups);
    ql_finalize<<<1, 256, 0, stream>>>(partials, nblk, preds, target,
                                       (float*)d_out, rows, tail_start);
}